// Round 4
// baseline (1882.775 us; speedup 1.0000x reference)
//
#include <hip/hip_runtime.h>
#include <hip/hip_bf16.h>

constexpr int S   = 10;
constexpr int Bsz = 16384;
constexpr int LAG = 5;
constexpr int H   = 512;
constexpr int G4  = 4 * H;            // 2048
constexpr int F   = 5;
constexpr int BH  = Bsz * H;          // 8388608
constexpr int OUT_HN = Bsz * (S + F); // 245760
constexpr int OUT_CN = OUT_HN + 2 * BH;

// GEMM tile geometry: 128 batch x (4 gates x 32 units), TK=32 half-tiles,
// 2-buffer LDS pipeline. 256 threads, 4 waves (2M x 2N). 37 KB LDS ->
// 4 blocks/CU co-resident.
constexpr int TK   = 32;
constexpr int NBUF = 2;
constexpr int A_T  = 128 * TK;        // 4096 shorts = 8 KB per buffer
constexpr int B_T  = 128 * TK;        // 4096 shorts = 8 KB per buffer

typedef __attribute__((ext_vector_type(8))) short short8;   // 8 bf16 = 4 VGPRs
typedef __attribute__((ext_vector_type(4))) float f32x4;

__device__ __forceinline__ float sigf(float x) { return 1.0f / (1.0f + __expf(-x)); }
__device__ __forceinline__ float tanh_fast(float x) {
    float e = __expf(2.0f * x);
    return 1.0f - 2.0f / (e + 1.0f);
}

__device__ __forceinline__ void gload_lds16(const void* g, void* l) {
    __builtin_amdgcn_global_load_lds(
        (const __attribute__((address_space(1))) unsigned int*)g,
        (__attribute__((address_space(3))) unsigned int*)l, 16, 0, 0);
}

// ---------------------------------------------------------------------------
// Prep (gate-major):
//   W0b = bf16(Whh0) [2048,512];  W1b = bf16([Wih1 | Whh1]) [2048,1024]
//   A0r = Wih0 @ W_in [2048,5];   b0 = Wih0@b_in + bih0 + bhh0;  b1 = bih1+bhh1
// ---------------------------------------------------------------------------
__global__ __launch_bounds__(256)
void prep_kernel(const float* __restrict__ W_in,  const float* __restrict__ b_in,
                 const float* __restrict__ Wih0,  const float* __restrict__ Whh0,
                 const float* __restrict__ bih0,  const float* __restrict__ bhh0,
                 const float* __restrict__ Wih1,  const float* __restrict__ Whh1,
                 const float* __restrict__ bih1,  const float* __restrict__ bhh1,
                 __hip_bfloat16* __restrict__ W0b, __hip_bfloat16* __restrict__ W1b,
                 float* __restrict__ A0r, float* __restrict__ b0r,
                 float* __restrict__ b1r)
{
    const int r   = blockIdx.x;   // 0..2047, gate-major (PyTorch order)
    const int tid = threadIdx.x;

    for (int k = tid; k < H; k += 256)
        W0b[r * H + k] = __float2bfloat16(Whh0[r * H + k]);
    for (int k = tid; k < 2 * H; k += 256)
        W1b[r * 2 * H + k] = __float2bfloat16(
            (k < H) ? Wih1[r * H + k] : Whh1[r * H + (k - H)]);

    if (tid < LAG) {
        float s = 0.f;
        for (int h = 0; h < H; ++h) s += Wih0[r * H + h] * W_in[h * LAG + tid];
        A0r[r * LAG + tid] = s;
    } else if (tid == 5) {
        float s = 0.f;
        for (int h = 0; h < H; ++h) s += Wih0[r * H + h] * b_in[h];
        b0r[r] = s + bih0[r] + bhh0[r];
    } else if (tid == 6) {
        b1r[r] = bih1[r] + bhh1[r];
    }
}

// ---------------------------------------------------------------------------
// MFMA GEMM + fused LSTM cell. 128x128 tile, 4 waves (2x2), TK=32 half-tiles,
// 2-buffer pipeline: stage(t+1) BEFORE compute(t), single vmcnt(0)+s_barrier
// AFTER compute (T3-minimum 2-phase).
// LDS rows are 64 B = 4 x 16B chunks. Bank-conflict-free swizzle:
//   physical chunk p = j ^ ((row>>1) & 3)
// -> (4*row + p) mod 8 covers all 8 bank-quads over 16 consecutive rows
// (2 lanes/quad = wave64 floor, measured-free regime). Applied as
// inverse-swizzled GLOBAL source + linear global_load_lds dest + swizzled
// read chunk (constant per lane: quad ^ ((li>>1)&3)).
// ---------------------------------------------------------------------------
__global__ __launch_bounds__(256)
void lstm_gemm(const __hip_bfloat16* __restrict__ Aseg0,
               const __hip_bfloat16* __restrict__ Aseg1,
               int nseg,                                  // 0, 1 or 2
               const __hip_bfloat16* __restrict__ W, int ldw,
               const float* __restrict__ bias,
               const float* __restrict__ xs,   // [B,5] or null
               const float* __restrict__ A0r,  // [2048,5] or null
               const float* __restrict__ c_in, // null => c_old = 0
               float* __restrict__ c_out,
               float* __restrict__ h32_out,    // fp32 h_n slot or null
               __hip_bfloat16* __restrict__ hb16_out, // bf16 h concat buffer
               int hcol)                       // 0 (layer0) or 512 (layer1)
{
    __shared__ __align__(16) short As[NBUF * A_T];   // 16 KB
    __shared__ __align__(16) short Bs[NBUF * B_T];   // 16 KB
    __shared__ float xls[128 * LAG];                 // 2.5 KB
    __shared__ float a0ls[128 * LAG];                // 2.5 KB

    const int tid  = threadIdx.x;
    const int lane = tid & 63;
    const int quad = lane >> 4;
    const int li   = lane & 15;
    const int wv   = tid >> 6;       // 0..3
    const int wy   = wv >> 1;        // 0..1  (M half, 64 rows)
    const int wx   = wv & 1;         // 0..1  (unit half, 16 units x 4 gates)

    // XCD-aware bijective swizzle: 2048 blocks = 8 x 256; each XCD gets
    // 16 contiguous batch panels x all 16 unit blocks -> A-panel L2 reuse.
    const int l  = blockIdx.y * gridDim.x + blockIdx.x;   // 0..2047
    const int v  = (l & 7) * 256 + (l >> 3);
    const int by = v >> 4;                        // 0..127 batch block
    const int bx = v & 15;                        // 0..15  unit block
    const int bM_ = by * 128;
    const int cn  = bx * 32;

    const bool has_x = (xs != nullptr);
    if (has_x) {
        for (int i = tid; i < 128 * LAG; i += 256) {
            const int row = i / LAG, ll = i % LAG;
            xls[i] = xs[(size_t)(bM_ + row) * LAG + ll];
        }
        for (int i = tid; i < 128 * LAG; i += 256) {
            const int cl = i / LAG, ll = i % LAG;      // cl = g*32+nn
            const int r  = (cl >> 5) * H + cn + (cl & 31);
            a0ls[i] = A0r[r * LAG + ll];
        }
        __syncthreads();
    }

    f32x4 acc[4][4];  // [m-frag][gate]
    #pragma unroll
    for (int i = 0; i < 4; ++i)
        #pragma unroll
        for (int j = 0; j < 4; ++j) acc[i][j] = (f32x4){0.f, 0.f, 0.f, 0.f};

    // staging geometry: per thread 2 A-chunks + 2 B-chunks (16 B) per half-tile.
    // Source chunk is inverse-swizzled (j ^ ((row>>1)&3)); LDS dest linear.
    int a_off[2], w_off[2];
    #pragma unroll
    for (int r = 0; r < 2; ++r) {
        const int idx = r * 256 + tid;            // 0..511
        const int row = idx >> 2;                 // 0..127
        const int j   = idx & 3;                  // logical dest chunk
        const int js  = j ^ ((row >> 1) & 3);     // swizzled source chunk
        a_off[r] = (bM_ + row) * 1024 + js * 8;   // hcat row stride = 1024
        const int rr = (row >> 5) * H + cn + (row & 31);   // gate-major W row
        w_off[r] = rr * ldw + js * 8;
    }

    const int NT = nseg * 16;                     // half-tiles of K=32

    auto stage_tile = [&](int t) {
        const int seg = t >> 4;
        const int kof = seg * 512 + (t & 15) * TK;   // = t*32 overall (shorts)
        const short* pa = (const short*)(seg ? Aseg1 : Aseg0) + kof;
        const short* pw = (const short*)W + kof;
        short* as = As + (t & 1) * A_T;
        short* bs = Bs + (t & 1) * B_T;
        #pragma unroll
        for (int r = 0; r < 2; ++r) {
            const int idx = r * 256 + tid;
            gload_lds16(pa + a_off[r], &as[idx * 8]);
            gload_lds16(pw + w_off[r], &bs[idx * 8]);
        }
    };

    // read-side physical chunk: quad ^ ((li>>1)&3) — constant per lane
    const int pch = quad ^ ((li >> 1) & 3);

    auto compute_tile = [&](int t) {
        const short* as = As + (t & 1) * A_T;
        const short* bs = Bs + (t & 1) * B_T;
        short8 af[4], bf[4];
        #pragma unroll
        for (int m = 0; m < 4; ++m)
            af[m] = *(const short8*)&as[(wy * 64 + m * 16 + li) * TK + pch * 8];
        #pragma unroll
        for (int g = 0; g < 4; ++g)
            bf[g] = *(const short8*)&bs[(g * 32 + wx * 16 + li) * TK + pch * 8];
        __builtin_amdgcn_s_setprio(1);
        #pragma unroll
        for (int m = 0; m < 4; ++m)
            #pragma unroll
            for (int g = 0; g < 4; ++g)
                acc[m][g] = __builtin_amdgcn_mfma_f32_16x16x32_bf16(
                    af[m], bf[g], acc[m][g], 0, 0, 0);
        __builtin_amdgcn_s_setprio(0);
    };

    if (NT) {
        stage_tile(0);
        asm volatile("s_waitcnt vmcnt(0)\n\ts_barrier" ::: "memory");
        for (int t = 0; t < NT; ++t) {
            if (t + 1 < NT) stage_tile(t + 1);   // issue next loads FIRST
            compute_tile(t);                     // MFMA hides their latency
            asm volatile("s_waitcnt vmcnt(0)\n\ts_barrier" ::: "memory");
        }
    }

    // ---------------- epilogue: bias + x-fold + LSTM cell ----------------
    const int n = cn + wx * 16 + li;        // this lane's hidden unit
    float bias4[4], a0reg[4][LAG];
    #pragma unroll
    for (int g = 0; g < 4; ++g) bias4[g] = bias[g * H + n];
    if (has_x) {
        #pragma unroll
        for (int g = 0; g < 4; ++g)
            #pragma unroll
            for (int ll = 0; ll < LAG; ++ll)
                a0reg[g][ll] = a0ls[(g * 32 + wx * 16 + li) * LAG + ll];
    }

    #pragma unroll
    for (int mt = 0; mt < 4; ++mt) {
        #pragma unroll
        for (int reg = 0; reg < 4; ++reg) {
            const int b_loc = wy * 64 + mt * 16 + quad * 4 + reg;
            const int b     = bM_ + b_loc;
            float g4[4];
            #pragma unroll
            for (int g = 0; g < 4; ++g) g4[g] = acc[mt][g][reg] + bias4[g];
            if (has_x) {
                #pragma unroll
                for (int ll = 0; ll < LAG; ++ll) {
                    const float xv = xls[b_loc * LAG + ll];
                    #pragma unroll
                    for (int g = 0; g < 4; ++g) g4[g] = fmaf(xv, a0reg[g][ll], g4[g]);
                }
            }
            const float ig = sigf(g4[0]);
            const float fg = sigf(g4[1]);
            const float gg = tanh_fast(g4[2]);
            const float og = sigf(g4[3]);
            const float cold = c_in ? c_in[(size_t)b * H + n] : 0.f;
            const float cnew = fg * cold + ig * gg;
            const float hh   = og * tanh_fast(cnew);
            c_out[(size_t)b * H + n] = cnew;
            if (h32_out) h32_out[(size_t)b * H + n] = hh;
            hb16_out[(size_t)b * 1024 + hcol + n] = __float2bfloat16(hh);
        }
    }
}

// ---------------------------------------------------------------------------
// Per-step scalar head (+ forecast head on last step). One wave per row.
// Reads bf16 h1 from hcat (cols 512..1023).
// ---------------------------------------------------------------------------
__global__ __launch_bounds__(256)
void out_head(const __hip_bfloat16* __restrict__ hcat,
              const float* __restrict__ W_out, const float* __restrict__ b_out,
              const float* __restrict__ W_f,   const float* __restrict__ b_f,
              float* __restrict__ out, int s, int last)
{
    const int wave = threadIdx.x >> 6;
    const int lane = threadIdx.x & 63;
    const int b    = blockIdx.x * 4 + wave;

    const __hip_bfloat16* hrow = hcat + (size_t)b * 1024 + 512;
    short8 hv = *(const short8*)&hrow[lane * 8];
    float h8[8];
    #pragma unroll
    for (int i = 0; i < 8; ++i) {
        union { unsigned int u; float f; } cv;
        cv.u = ((unsigned int)(unsigned short)hv[i]) << 16;
        h8[i] = cv.f;
    }

    {
        const float4 w0 = *reinterpret_cast<const float4*>(&W_out[lane * 8]);
        const float4 w1 = *reinterpret_cast<const float4*>(&W_out[lane * 8 + 4]);
        const float w8[8] = {w0.x, w0.y, w0.z, w0.w, w1.x, w1.y, w1.z, w1.w};
        float v = 0.f;
        #pragma unroll
        for (int i = 0; i < 8; ++i) v = fmaf(h8[i], w8[i], v);
        #pragma unroll
        for (int off = 32; off > 0; off >>= 1) v += __shfl_down(v, off, 64);
        if (lane == 0) out[b * (S + F) + s] = v + b_out[0];
    }
    if (last) {
        for (int f = 0; f < F; ++f) {
            const float4 w0 = *reinterpret_cast<const float4*>(&W_f[f * H + lane * 8]);
            const float4 w1 = *reinterpret_cast<const float4*>(&W_f[f * H + lane * 8 + 4]);
            const float w8[8] = {w0.x, w0.y, w0.z, w0.w, w1.x, w1.y, w1.z, w1.w};
            float v = 0.f;
            #pragma unroll
            for (int i = 0; i < 8; ++i) v = fmaf(h8[i], w8[i], v);
            #pragma unroll
            for (int off = 32; off > 0; off >>= 1) v += __shfl_down(v, off, 64);
            if (lane == 0) out[b * (S + F) + S + f] = v + b_f[f];
        }
    }
}

// ---------------------------------------------------------------------------
extern "C" void kernel_launch(void* const* d_in, const int* in_sizes, int n_in,
                              void* d_out, int out_size, void* d_ws, size_t ws_size,
                              hipStream_t stream)
{
    const float* x     = (const float*)d_in[0];
    const float* W_in  = (const float*)d_in[1];
    const float* b_in  = (const float*)d_in[2];
    const float* Wih0  = (const float*)d_in[3];
    const float* Whh0  = (const float*)d_in[4];
    const float* bih0  = (const float*)d_in[5];
    const float* bhh0  = (const float*)d_in[6];
    const float* Wih1  = (const float*)d_in[7];
    const float* Whh1  = (const float*)d_in[8];
    const float* bih1  = (const float*)d_in[9];
    const float* bhh1  = (const float*)d_in[10];
    const float* W_out = (const float*)d_in[11];
    const float* b_out = (const float*)d_in[12];
    const float* W_f   = (const float*)d_in[13];
    const float* b_f   = (const float*)d_in[14];

    float* out = (float*)d_out;
    char*  ws  = (char*)d_ws;

    // workspace layout
    __hip_bfloat16* hcat0 = (__hip_bfloat16*)ws;                    // [B,1024]
    __hip_bfloat16* hcat1 = hcat0 + (size_t)Bsz * 1024;             // [B,1024]
    __hip_bfloat16* W0b   = hcat1 + (size_t)Bsz * 1024;             // [2048,512]
    __hip_bfloat16* W1b   = W0b + (size_t)G4 * H;                   // [2048,1024]
    float* A0r = (float*)(W1b + (size_t)G4 * 2 * H);                // [2048,5]
    float* b0r = A0r + G4 * LAG;
    float* b1r = b0r + G4;

    // d_out sections as state
    float* hn0 = out + OUT_HN;            // h0 fp32 (last step only)
    float* hn1 = out + OUT_HN + BH;       // h1 fp32 (last step only)
    float* c0  = out + OUT_CN;            // c0 in place
    float* c1  = out + OUT_CN + BH;       // c1 in place

    prep_kernel<<<dim3(G4), dim3(256), 0, stream>>>(
        W_in, b_in, Wih0, Whh0, bih0, bhh0, Wih1, Whh1, bih1, bhh1,
        W0b, W1b, A0r, b0r, b1r);

    __hip_bfloat16* hbuf[2] = {hcat0, hcat1};
    const dim3 grid(16, 128);   // 2048 blocks
    const dim3 blk(256);

    for (int s = 0; s < S; ++s) {
        const bool first = (s == 0);
        const bool last  = (s == S - 1);
        __hip_bfloat16* cur  = hbuf[s & 1];
        __hip_bfloat16* prev = hbuf[(s + 1) & 1];

        // layer 0: A = h0_prev (cols 0-511 of prev), K=512
        lstm_gemm<<<grid, blk, 0, stream>>>(
            prev, nullptr, first ? 0 : 1, W0b, H, b0r,
            x + (size_t)s * Bsz * LAG, A0r,
            first ? nullptr : c0, c0, last ? hn0 : nullptr, cur, 0);

        // layer 1: A = [h0_cur cols 0-511 | h1_prev cols 512-1023], K=1024
        lstm_gemm<<<grid, blk, 0, stream>>>(
            cur, prev, first ? 1 : 2, W1b, 2 * H, b1r,
            nullptr, nullptr,
            first ? nullptr : c1, c1, last ? hn1 : nullptr, cur, H);

        out_head<<<dim3(Bsz / 4), dim3(256), 0, stream>>>(
            cur, W_out, b_out, W_f, b_f, out, s, last ? 1 : 0);
    }
}

// Round 5
// 1693.880 us; speedup vs baseline: 1.1115x; 1.1115x over previous
//
#include <hip/hip_runtime.h>
#include <hip/hip_bf16.h>

constexpr int S   = 10;
constexpr int Bsz = 16384;
constexpr int LAG = 5;
constexpr int H   = 512;
constexpr int G4  = 4 * H;            // 2048
constexpr int F   = 5;
constexpr int BH  = Bsz * H;          // 8388608
constexpr int OUT_HN = Bsz * (S + F); // 245760
constexpr int OUT_CN = OUT_HN + 2 * BH;

// GEMM tile geometry: 256 batch x (4 gates x 32 units), TK=32 K-tiles,
// NBUF=3 LDS pipeline with counted vmcnt (depth-2 prefetch).
// 512 threads, 8 waves (4M x 2N). 79.5 KB LDS -> 2 blocks/CU.
constexpr int TK   = 32;
constexpr int NBUF = 3;
constexpr int BM   = 256;
constexpr int BNR  = 128;             // B rows = 4 gates x 32 units
constexpr int A_T  = BM  * TK;        // 8192 shorts = 16 KB per buffer
constexpr int B_T  = BNR * TK;        // 4096 shorts =  8 KB per buffer

typedef __attribute__((ext_vector_type(8))) short short8;   // 8 bf16 = 4 VGPRs
typedef __attribute__((ext_vector_type(4))) float f32x4;

__device__ __forceinline__ float sigf(float x) { return 1.0f / (1.0f + __expf(-x)); }
__device__ __forceinline__ float tanh_fast(float x) {
    float e = __expf(2.0f * x);
    return 1.0f - 2.0f / (e + 1.0f);
}

__device__ __forceinline__ void gload_lds16(const void* g, void* l) {
    __builtin_amdgcn_global_load_lds(
        (const __attribute__((address_space(1))) unsigned int*)g,
        (__attribute__((address_space(3))) unsigned int*)l, 16, 0, 0);
}

// ---------------------------------------------------------------------------
// Prep (gate-major):
//   W0b = bf16(Whh0) [2048,512];  W1b = bf16([Wih1 | Whh1]) [2048,1024]
//   A0r = Wih0 @ W_in [2048,5];   b0 = Wih0@b_in + bih0 + bhh0;  b1 = bih1+bhh1
// ---------------------------------------------------------------------------
__global__ __launch_bounds__(256)
void prep_kernel(const float* __restrict__ W_in,  const float* __restrict__ b_in,
                 const float* __restrict__ Wih0,  const float* __restrict__ Whh0,
                 const float* __restrict__ bih0,  const float* __restrict__ bhh0,
                 const float* __restrict__ Wih1,  const float* __restrict__ Whh1,
                 const float* __restrict__ bih1,  const float* __restrict__ bhh1,
                 __hip_bfloat16* __restrict__ W0b, __hip_bfloat16* __restrict__ W1b,
                 float* __restrict__ A0r, float* __restrict__ b0r,
                 float* __restrict__ b1r)
{
    const int r   = blockIdx.x;   // 0..2047, gate-major (PyTorch order)
    const int tid = threadIdx.x;

    for (int k = tid; k < H; k += 256)
        W0b[r * H + k] = __float2bfloat16(Whh0[r * H + k]);
    for (int k = tid; k < 2 * H; k += 256)
        W1b[r * 2 * H + k] = __float2bfloat16(
            (k < H) ? Wih1[r * H + k] : Whh1[r * H + (k - H)]);

    if (tid < LAG) {
        float s = 0.f;
        for (int h = 0; h < H; ++h) s += Wih0[r * H + h] * W_in[h * LAG + tid];
        A0r[r * LAG + tid] = s;
    } else if (tid == 5) {
        float s = 0.f;
        for (int h = 0; h < H; ++h) s += Wih0[r * H + h] * b_in[h];
        b0r[r] = s + bih0[r] + bhh0[r];
    } else if (tid == 6) {
        b1r[r] = bih1[r] + bhh1[r];
    }
}

// ---------------------------------------------------------------------------
// MFMA GEMM + fused LSTM cell. 256x128 tile, 8 waves (4M x 2N), TK=32,
// NBUF=3 with counted vmcnt: at top of iter t wait vmcnt(3) (tile t done,
// tile t+1's 3 loads in flight), stage tile t+2 during the two compute
// phases. Loads get ~2 K-tile periods to land; vmcnt never drains to 0
// in the main loop (T4). Buffer (t+2)%3 was last read in iter t-1 with a
// barrier since -> race-free.
// LDS rows 64 B = 4 x 16B chunks, physical chunk p = j ^ ((row>>1)&3):
// r4-measured ZERO bank conflicts. Inverse-swizzled global source +
// linear global_load_lds dest + per-lane constant read chunk.
// ---------------------------------------------------------------------------
__global__ __launch_bounds__(512, 4)
void lstm_gemm(const __hip_bfloat16* __restrict__ Aseg0,
               const __hip_bfloat16* __restrict__ Aseg1,
               int nseg,                                  // 0, 1 or 2
               const __hip_bfloat16* __restrict__ W, int ldw,
               const float* __restrict__ bias,
               const float* __restrict__ xs,   // [B,5] or null
               const float* __restrict__ A0r,  // [2048,5] or null
               const float* __restrict__ c_in, // null => c_old = 0
               float* __restrict__ c_out,
               float* __restrict__ h32_out,    // fp32 h_n slot or null
               __hip_bfloat16* __restrict__ hb16_out, // bf16 h concat buffer
               int hcol)                       // 0 (layer0) or 512 (layer1)
{
    __shared__ __align__(16) short As[NBUF * A_T];   // 48 KB
    __shared__ __align__(16) short Bs[NBUF * B_T];   // 24 KB
    __shared__ float xls[BM * LAG];                  // 5 KB
    __shared__ float a0ls[BNR * LAG];                // 2.5 KB

    const int tid  = threadIdx.x;
    const int lane = tid & 63;
    const int quad = lane >> 4;
    const int li   = lane & 15;
    const int wv   = tid >> 6;       // 0..7
    const int wy   = wv >> 1;        // 0..3  (M quarter, 64 rows)
    const int wx   = wv & 1;         // 0..1  (unit half, 16 units x 4 gates)

    // XCD-aware bijective swizzle: 1024 blocks = 8 x 128; each XCD gets
    // 8 contiguous batch panels x all 16 unit blocks -> A-panel L2 reuse.
    const int l  = blockIdx.y * gridDim.x + blockIdx.x;   // 0..1023
    const int v  = (l & 7) * 128 + (l >> 3);
    const int by = v >> 4;                        // 0..63 batch block
    const int bx = v & 15;                        // 0..15 unit block
    const int bM_ = by * BM;
    const int cn  = bx * 32;

    const bool has_x = (xs != nullptr);
    if (has_x) {
        for (int i = tid; i < BM * LAG; i += 512) {
            const int row = i / LAG, ll = i % LAG;
            xls[i] = xs[(size_t)(bM_ + row) * LAG + ll];
        }
        for (int i = tid; i < BNR * LAG; i += 512) {
            const int cl = i / LAG, ll = i % LAG;      // cl = g*32+nn
            const int r  = (cl >> 5) * H + cn + (cl & 31);
            a0ls[i] = A0r[r * LAG + ll];
        }
        __syncthreads();
    }

    f32x4 acc[4][4];  // [m-frag][gate]
    #pragma unroll
    for (int i = 0; i < 4; ++i)
        #pragma unroll
        for (int j = 0; j < 4; ++j) acc[i][j] = (f32x4){0.f, 0.f, 0.f, 0.f};

    // staging geometry: per thread 2 A-chunks + 1 B-chunk (16 B) per K-tile.
    // Source chunk inverse-swizzled (j ^ ((row>>1)&3)); LDS dest linear.
    int a_off[2], w_off;
    #pragma unroll
    for (int r = 0; r < 2; ++r) {
        const int idx = r * 512 + tid;            // 0..1023
        const int row = idx >> 2;                 // 0..255
        const int j   = idx & 3;                  // logical dest chunk
        const int js  = j ^ ((row >> 1) & 3);     // swizzled source chunk
        a_off[r] = (bM_ + row) * 1024 + js * 8;   // hcat row stride = 1024
    }
    {
        const int row = tid >> 2;                 // 0..127 (gate*32+unit)
        const int j   = tid & 3;
        const int js  = j ^ ((row >> 1) & 3);
        const int rr  = (row >> 5) * H + cn + (row & 31);   // gate-major W row
        w_off = rr * ldw + js * 8;
    }

    const int NT = nseg * 16;                     // K-tiles of 32

    auto stage_A = [&](int t) {
        const int seg = t >> 4;
        const int kof = seg * 512 + (t & 15) * TK;
        const short* pa = (const short*)(seg ? Aseg1 : Aseg0) + kof;
        short* as = As + (t % NBUF) * A_T;
        #pragma unroll
        for (int r = 0; r < 2; ++r)
            gload_lds16(pa + a_off[r], &as[(r * 512 + tid) * 8]);
    };
    auto stage_B = [&](int t) {
        const int seg = t >> 4;
        const int kof = seg * 512 + (t & 15) * TK;
        const short* pw = (const short*)W + kof;
        short* bs = Bs + (t % NBUF) * B_T;
        gload_lds16(pw + w_off, &bs[tid * 8]);
    };

    // read-side physical chunk: quad ^ ((li>>1)&3) — constant per lane
    const int pch = quad ^ ((li >> 1) & 3);

    if (NT) {
        stage_A(0); stage_B(0);
        stage_A(1); stage_B(1);
        for (int t = 0; t < NT; ++t) {
            if (t + 1 < NT) {
                // tile t complete; tile t+1's 3 loads stay in flight
                asm volatile("s_waitcnt vmcnt(3)\n\ts_barrier" ::: "memory");
            } else {
                asm volatile("s_waitcnt vmcnt(0)\n\ts_barrier" ::: "memory");
            }
            const short* as = As + (t % NBUF) * A_T;
            const short* bs = Bs + (t % NBUF) * B_T;

            // ---- phase 0: B frags + A frags m0,m1; stage A of t+2 ----
            short8 bf[4], af0, af1;
            #pragma unroll
            for (int g = 0; g < 4; ++g)
                bf[g] = *(const short8*)&bs[(g * 32 + wx * 16 + li) * TK + pch * 8];
            af0 = *(const short8*)&as[(wy * 64 + 0 * 16 + li) * TK + pch * 8];
            af1 = *(const short8*)&as[(wy * 64 + 1 * 16 + li) * TK + pch * 8];
            if (t + 2 < NT) stage_A(t + 2);
            asm volatile("s_barrier" ::: "memory");
            __builtin_amdgcn_s_setprio(1);
            #pragma unroll
            for (int g = 0; g < 4; ++g)
                acc[0][g] = __builtin_amdgcn_mfma_f32_16x16x32_bf16(
                    af0, bf[g], acc[0][g], 0, 0, 0);
            #pragma unroll
            for (int g = 0; g < 4; ++g)
                acc[1][g] = __builtin_amdgcn_mfma_f32_16x16x32_bf16(
                    af1, bf[g], acc[1][g], 0, 0, 0);
            __builtin_amdgcn_s_setprio(0);

            // ---- phase 1: A frags m2,m3; stage B of t+2 ----
            short8 af2, af3;
            af2 = *(const short8*)&as[(wy * 64 + 2 * 16 + li) * TK + pch * 8];
            af3 = *(const short8*)&as[(wy * 64 + 3 * 16 + li) * TK + pch * 8];
            if (t + 2 < NT) stage_B(t + 2);
            asm volatile("s_barrier" ::: "memory");
            __builtin_amdgcn_s_setprio(1);
            #pragma unroll
            for (int g = 0; g < 4; ++g)
                acc[2][g] = __builtin_amdgcn_mfma_f32_16x16x32_bf16(
                    af2, bf[g], acc[2][g], 0, 0, 0);
            #pragma unroll
            for (int g = 0; g < 4; ++g)
                acc[3][g] = __builtin_amdgcn_mfma_f32_16x16x32_bf16(
                    af3, bf[g], acc[3][g], 0, 0, 0);
            __builtin_amdgcn_s_setprio(0);
        }
    }

    // ---------------- epilogue: bias + x-fold + LSTM cell ----------------
    const int n = cn + wx * 16 + li;        // this lane's hidden unit
    float bias4[4], a0reg[4][LAG];
    #pragma unroll
    for (int g = 0; g < 4; ++g) bias4[g] = bias[g * H + n];
    if (has_x) {
        #pragma unroll
        for (int g = 0; g < 4; ++g)
            #pragma unroll
            for (int ll = 0; ll < LAG; ++ll)
                a0reg[g][ll] = a0ls[(g * 32 + wx * 16 + li) * LAG + ll];
    }

    #pragma unroll
    for (int mt = 0; mt < 4; ++mt) {
        #pragma unroll
        for (int reg = 0; reg < 4; ++reg) {
            const int b_loc = wy * 64 + mt * 16 + quad * 4 + reg;
            const int b     = bM_ + b_loc;
            float g4[4];
            #pragma unroll
            for (int g = 0; g < 4; ++g) g4[g] = acc[mt][g][reg] + bias4[g];
            if (has_x) {
                #pragma unroll
                for (int ll = 0; ll < LAG; ++ll) {
                    const float xv = xls[b_loc * LAG + ll];
                    #pragma unroll
                    for (int g = 0; g < 4; ++g) g4[g] = fmaf(xv, a0reg[g][ll], g4[g]);
                }
            }
            const float ig = sigf(g4[0]);
            const float fg = sigf(g4[1]);
            const float gg = tanh_fast(g4[2]);
            const float og = sigf(g4[3]);
            const float cold = c_in ? c_in[(size_t)b * H + n] : 0.f;
            const float cnew = fg * cold + ig * gg;
            const float hh   = og * tanh_fast(cnew);
            c_out[(size_t)b * H + n] = cnew;
            if (h32_out) h32_out[(size_t)b * H + n] = hh;
            hb16_out[(size_t)b * 1024 + hcol + n] = __float2bfloat16(hh);
        }
    }
}

// ---------------------------------------------------------------------------
// Per-step scalar head (+ forecast head on last step). One wave per row.
// Reads bf16 h1 from hcat (cols 512..1023).
// ---------------------------------------------------------------------------
__global__ __launch_bounds__(256)
void out_head(const __hip_bfloat16* __restrict__ hcat,
              const float* __restrict__ W_out, const float* __restrict__ b_out,
              const float* __restrict__ W_f,   const float* __restrict__ b_f,
              float* __restrict__ out, int s, int last)
{
    const int wave = threadIdx.x >> 6;
    const int lane = threadIdx.x & 63;
    const int b    = blockIdx.x * 4 + wave;

    const __hip_bfloat16* hrow = hcat + (size_t)b * 1024 + 512;
    short8 hv = *(const short8*)&hrow[lane * 8];
    float h8[8];
    #pragma unroll
    for (int i = 0; i < 8; ++i) {
        union { unsigned int u; float f; } cv;
        cv.u = ((unsigned int)(unsigned short)hv[i]) << 16;
        h8[i] = cv.f;
    }

    {
        const float4 w0 = *reinterpret_cast<const float4*>(&W_out[lane * 8]);
        const float4 w1 = *reinterpret_cast<const float4*>(&W_out[lane * 8 + 4]);
        const float w8[8] = {w0.x, w0.y, w0.z, w0.w, w1.x, w1.y, w1.z, w1.w};
        float v = 0.f;
        #pragma unroll
        for (int i = 0; i < 8; ++i) v = fmaf(h8[i], w8[i], v);
        #pragma unroll
        for (int off = 32; off > 0; off >>= 1) v += __shfl_down(v, off, 64);
        if (lane == 0) out[b * (S + F) + s] = v + b_out[0];
    }
    if (last) {
        for (int f = 0; f < F; ++f) {
            const float4 w0 = *reinterpret_cast<const float4*>(&W_f[f * H + lane * 8]);
            const float4 w1 = *reinterpret_cast<const float4*>(&W_f[f * H + lane * 8 + 4]);
            const float w8[8] = {w0.x, w0.y, w0.z, w0.w, w1.x, w1.y, w1.z, w1.w};
            float v = 0.f;
            #pragma unroll
            for (int i = 0; i < 8; ++i) v = fmaf(h8[i], w8[i], v);
            #pragma unroll
            for (int off = 32; off > 0; off >>= 1) v += __shfl_down(v, off, 64);
            if (lane == 0) out[b * (S + F) + S + f] = v + b_f[f];
        }
    }
}

// ---------------------------------------------------------------------------
extern "C" void kernel_launch(void* const* d_in, const int* in_sizes, int n_in,
                              void* d_out, int out_size, void* d_ws, size_t ws_size,
                              hipStream_t stream)
{
    const float* x     = (const float*)d_in[0];
    const float* W_in  = (const float*)d_in[1];
    const float* b_in  = (const float*)d_in[2];
    const float* Wih0  = (const float*)d_in[3];
    const float* Whh0  = (const float*)d_in[4];
    const float* bih0  = (const float*)d_in[5];
    const float* bhh0  = (const float*)d_in[6];
    const float* Wih1  = (const float*)d_in[7];
    const float* Whh1  = (const float*)d_in[8];
    const float* bih1  = (const float*)d_in[9];
    const float* bhh1  = (const float*)d_in[10];
    const float* W_out = (const float*)d_in[11];
    const float* b_out = (const float*)d_in[12];
    const float* W_f   = (const float*)d_in[13];
    const float* b_f   = (const float*)d_in[14];

    float* out = (float*)d_out;
    char*  ws  = (char*)d_ws;

    // workspace layout
    __hip_bfloat16* hcat0 = (__hip_bfloat16*)ws;                    // [B,1024]
    __hip_bfloat16* hcat1 = hcat0 + (size_t)Bsz * 1024;             // [B,1024]
    __hip_bfloat16* W0b   = hcat1 + (size_t)Bsz * 1024;             // [2048,512]
    __hip_bfloat16* W1b   = W0b + (size_t)G4 * H;                   // [2048,1024]
    float* A0r = (float*)(W1b + (size_t)G4 * 2 * H);                // [2048,5]
    float* b0r = A0r + G4 * LAG;
    float* b1r = b0r + G4;

    // d_out sections as state
    float* hn0 = out + OUT_HN;            // h0 fp32 (last step only)
    float* hn1 = out + OUT_HN + BH;       // h1 fp32 (last step only)
    float* c0  = out + OUT_CN;            // c0 in place
    float* c1  = out + OUT_CN + BH;       // c1 in place

    prep_kernel<<<dim3(G4), dim3(256), 0, stream>>>(
        W_in, b_in, Wih0, Whh0, bih0, bhh0, Wih1, Whh1, bih1, bhh1,
        W0b, W1b, A0r, b0r, b1r);

    __hip_bfloat16* hbuf[2] = {hcat0, hcat1};
    const dim3 grid(16, 64);   // 1024 blocks
    const dim3 blk(512);

    for (int s = 0; s < S; ++s) {
        const bool first = (s == 0);
        const bool last  = (s == S - 1);
        __hip_bfloat16* cur  = hbuf[s & 1];
        __hip_bfloat16* prev = hbuf[(s + 1) & 1];

        // layer 0: A = h0_prev (cols 0-511 of prev), K=512
        lstm_gemm<<<grid, blk, 0, stream>>>(
            prev, nullptr, first ? 0 : 1, W0b, H, b0r,
            x + (size_t)s * Bsz * LAG, A0r,
            first ? nullptr : c0, c0, last ? hn0 : nullptr, cur, 0);

        // layer 1: A = [h0_cur cols 0-511 | h1_prev cols 512-1023], K=1024
        lstm_gemm<<<grid, blk, 0, stream>>>(
            cur, prev, first ? 1 : 2, W1b, 2 * H, b1r,
            nullptr, nullptr,
            first ? nullptr : c1, c1, last ? hn1 : nullptr, cur, H);

        out_head<<<dim3(Bsz / 4), dim3(256), 0, stream>>>(
            cur, W_out, b_out, W_f, b_f, out, s, last ? 1 : 0);
    }
}

// Round 6
// 1651.461 us; speedup vs baseline: 1.1401x; 1.0257x over previous
//
#include <hip/hip_runtime.h>
#include <hip/hip_bf16.h>

constexpr int S   = 10;
constexpr int Bsz = 16384;
constexpr int LAG = 5;
constexpr int H   = 512;
constexpr int G4  = 4 * H;            // 2048
constexpr int F   = 5;
constexpr int BH  = Bsz * H;          // 8388608
constexpr int OUT_HN = Bsz * (S + F); // 245760
constexpr int OUT_CN = OUT_HN + 2 * BH;

// GEMM tile geometry: 256 batch x (4 gates x 32 units), TK=32 K-tiles,
// NBUF=3 LDS pipeline with counted vmcnt (depth-2 prefetch), FULLY UNROLLED
// K-loop (compile-time tile index: zero per-tile VALU addressing).
// 512 threads, 8 waves (4M x 2N). 79.5 KB LDS -> 2 blocks/CU.
constexpr int TK   = 32;
constexpr int NBUF = 3;
constexpr int BM   = 256;
constexpr int BNR  = 128;             // B rows = 4 gates x 32 units
constexpr int A_T  = BM  * TK;        // 8192 shorts = 16 KB per buffer
constexpr int B_T  = BNR * TK;        // 4096 shorts =  8 KB per buffer

typedef __attribute__((ext_vector_type(8))) short short8;   // 8 bf16 = 4 VGPRs
typedef __attribute__((ext_vector_type(4))) float f32x4;

template <int I> struct Int { static constexpr int val = I; };

template <int N, typename F>
__device__ __forceinline__ void static_for(F&& f) {
    if constexpr (N > 0) {
        static_for<N - 1>(f);
        f(Int<N - 1>{});
    }
}

__device__ __forceinline__ float sigf(float x) { return 1.0f / (1.0f + __expf(-x)); }
__device__ __forceinline__ float tanh_fast(float x) {
    float e = __expf(2.0f * x);
    return 1.0f - 2.0f / (e + 1.0f);
}

__device__ __forceinline__ void gload_lds16(const void* g, void* l) {
    __builtin_amdgcn_global_load_lds(
        (const __attribute__((address_space(1))) unsigned int*)g,
        (__attribute__((address_space(3))) unsigned int*)l, 16, 0, 0);
}

// ---------------------------------------------------------------------------
// Prep (gate-major):
//   W0b = bf16(Whh0) [2048,512];  W1b = bf16([Wih1 | Whh1]) [2048,1024]
//   A0r = Wih0 @ W_in [2048,5];   b0 = Wih0@b_in + bih0 + bhh0;  b1 = bih1+bhh1
// ---------------------------------------------------------------------------
__global__ __launch_bounds__(256)
void prep_kernel(const float* __restrict__ W_in,  const float* __restrict__ b_in,
                 const float* __restrict__ Wih0,  const float* __restrict__ Whh0,
                 const float* __restrict__ bih0,  const float* __restrict__ bhh0,
                 const float* __restrict__ Wih1,  const float* __restrict__ Whh1,
                 const float* __restrict__ bih1,  const float* __restrict__ bhh1,
                 __hip_bfloat16* __restrict__ W0b, __hip_bfloat16* __restrict__ W1b,
                 float* __restrict__ A0r, float* __restrict__ b0r,
                 float* __restrict__ b1r)
{
    const int r   = blockIdx.x;   // 0..2047, gate-major (PyTorch order)
    const int tid = threadIdx.x;

    for (int k = tid; k < H; k += 256)
        W0b[r * H + k] = __float2bfloat16(Whh0[r * H + k]);
    for (int k = tid; k < 2 * H; k += 256)
        W1b[r * 2 * H + k] = __float2bfloat16(
            (k < H) ? Wih1[r * H + k] : Whh1[r * H + (k - H)]);

    if (tid < LAG) {
        float s = 0.f;
        for (int h = 0; h < H; ++h) s += Wih0[r * H + h] * W_in[h * LAG + tid];
        A0r[r * LAG + tid] = s;
    } else if (tid == 5) {
        float s = 0.f;
        for (int h = 0; h < H; ++h) s += Wih0[r * H + h] * b_in[h];
        b0r[r] = s + bih0[r] + bhh0[r];
    } else if (tid == 6) {
        b1r[r] = bih1[r] + bhh1[r];
    }
}

// ---------------------------------------------------------------------------
// MFMA GEMM + fused LSTM cell. 256x128 tile, 8 waves (4M x 2N), TK=32,
// NBUF=3, counted vmcnt depth-2 (r5-proven schedule), K-loop FULLY UNROLLED:
// NT is a template param so buffer rotation (t%3), global offsets (t*64B)
// and LDS offsets all fold to immediates. ONE barrier per K-tile
// (vmcnt(3)+s_barrier at tile top: all waves' tile-t loads retired).
// A is a SINGLE contiguous buffer (rows of hcat; L1's [h0|h1] made
// contiguous by writing h1 into the next step's buffer).
// LDS rows 64 B = 4 x 16B chunks, source chunk j ^ ((row>>1)&3):
// r4/r5-measured ZERO bank conflicts.
// ---------------------------------------------------------------------------
template <int NT>   // K-tiles of 32: 0 (skip GEMM), 16 (K=512), 32 (K=1024)
__global__ __launch_bounds__(512, 4)
void lstm_gemm(const __hip_bfloat16* __restrict__ A,   // [B,1024] bf16 rows
               const __hip_bfloat16* __restrict__ W, int ldw,
               const float* __restrict__ bias,
               const float* __restrict__ xs,   // [B,5] or null
               const float* __restrict__ A0r,  // [2048,5] or null
               const float* __restrict__ c_in, // null => c_old = 0
               float* __restrict__ c_out,
               float* __restrict__ h32_out,    // fp32 h_n slot or null
               __hip_bfloat16* __restrict__ hb16_out, // bf16 h dest buffer
               int hcol)                       // 0 (layer0) or 512 (layer1)
{
    __shared__ __align__(16) short As[NBUF * A_T];   // 48 KB
    __shared__ __align__(16) short Bs[NBUF * B_T];   // 24 KB
    __shared__ float xls[BM * LAG];                  // 5 KB
    __shared__ float a0ls[BNR * LAG];                // 2.5 KB

    const int tid  = threadIdx.x;
    const int lane = tid & 63;
    const int quad = lane >> 4;
    const int li   = lane & 15;
    const int wv   = tid >> 6;       // 0..7
    const int wy   = wv >> 1;        // 0..3  (M quarter, 64 rows)
    const int wx   = wv & 1;         // 0..1  (unit half, 16 units x 4 gates)

    // XCD-aware bijective swizzle: 1024 blocks = 8 x 128; each XCD gets
    // 8 contiguous batch panels x all 16 unit blocks -> A-panel L2 reuse.
    const int l  = blockIdx.y * gridDim.x + blockIdx.x;   // 0..1023
    const int v  = (l & 7) * 128 + (l >> 3);
    const int by = v >> 4;                        // 0..63 batch block
    const int bx = v & 15;                        // 0..15 unit block
    const int bM_ = by * BM;
    const int cn  = bx * 32;

    const bool has_x = (xs != nullptr);
    if (has_x) {
        for (int i = tid; i < BM * LAG; i += 512) {
            const int row = i / LAG, ll = i % LAG;
            xls[i] = xs[(size_t)(bM_ + row) * LAG + ll];
        }
        for (int i = tid; i < BNR * LAG; i += 512) {
            const int cl = i / LAG, ll = i % LAG;      // cl = g*32+nn
            const int r  = (cl >> 5) * H + cn + (cl & 31);
            a0ls[i] = A0r[r * LAG + ll];
        }
        __syncthreads();
    }

    f32x4 acc[4][4];  // [m-frag][gate]
    #pragma unroll
    for (int i = 0; i < 4; ++i)
        #pragma unroll
        for (int j = 0; j < 4; ++j) acc[i][j] = (f32x4){0.f, 0.f, 0.f, 0.f};

    if constexpr (NT > 0) {
        // per-thread staging geometry: 2 A-chunks + 1 B-chunk (16B) per tile.
        // Source chunk inverse-swizzled (j ^ ((row>>1)&3)); LDS dest linear.
        const short* Ab = (const short*)A;
        const short* Wb = (const short*)W;
        int a_off0, a_off1, w_off;
        {
            const int row0 = tid >> 2, j0 = tid & 3;
            a_off0 = (bM_ + row0) * 1024 + (j0 ^ ((row0 >> 1) & 3)) * 8;
            const int idx1 = 512 + tid;
            const int row1 = idx1 >> 2, j1 = idx1 & 3;
            a_off1 = (bM_ + row1) * 1024 + (j1 ^ ((row1 >> 1) & 3)) * 8;
            const int rw = tid >> 2, jw = tid & 3;
            const int rr = (rw >> 5) * H + cn + (rw & 31);   // gate-major W row
            w_off = rr * ldw + (jw ^ ((rw >> 1) & 3)) * 8;
        }
        const int adst0 = tid * 8;            // shorts
        const int adst1 = (512 + tid) * 8;
        const int bdst  = tid * 8;

        auto stage = [&](auto tc) {
            constexpr int t   = decltype(tc)::val;
            constexpr int buf = t % NBUF;
            gload_lds16(Ab + t * TK + a_off0, &As[buf * A_T + adst0]);
            gload_lds16(Ab + t * TK + a_off1, &As[buf * A_T + adst1]);
            gload_lds16(Wb + t * TK + w_off,  &Bs[buf * B_T + bdst]);
        };

        // read-side physical chunk: quad ^ ((li>>1)&3) — constant per lane
        const int pch = quad ^ ((li >> 1) & 3);
        const int arow = (wy * 64 + li) * TK + pch * 8;       // + m*16*TK
        const int brow = (wx * 16 + li) * TK + pch * 8;       // + g*32*TK

        stage(Int<0>{});
        stage(Int<1>{});

        static_for<NT>([&](auto tc) {
            constexpr int t   = decltype(tc)::val;
            constexpr int buf = t % NBUF;
            if constexpr (t + 1 < NT)
                // tile t complete everywhere; tile t+1's 3 loads in flight
                asm volatile("s_waitcnt vmcnt(3)\n\ts_barrier" ::: "memory");
            else
                asm volatile("s_waitcnt vmcnt(0)\n\ts_barrier" ::: "memory");

            const short* as = As + buf * A_T;
            const short* bs = Bs + buf * B_T;
            short8 af[4], bf[4];
            #pragma unroll
            for (int m = 0; m < 4; ++m)
                af[m] = *(const short8*)&as[arow + m * 16 * TK];
            #pragma unroll
            for (int g = 0; g < 4; ++g)
                bf[g] = *(const short8*)&bs[brow + g * 32 * TK];

            if constexpr (t + 2 < NT) stage(Int<t + 2>{});

            __builtin_amdgcn_s_setprio(1);
            #pragma unroll
            for (int m = 0; m < 4; ++m)
                #pragma unroll
                for (int g = 0; g < 4; ++g)
                    acc[m][g] = __builtin_amdgcn_mfma_f32_16x16x32_bf16(
                        af[m], bf[g], acc[m][g], 0, 0, 0);
            __builtin_amdgcn_s_setprio(0);
        });
    }

    // ---------------- epilogue: bias + x-fold + LSTM cell ----------------
    const int n = cn + wx * 16 + li;        // this lane's hidden unit
    float bias4[4], a0reg[4][LAG];
    #pragma unroll
    for (int g = 0; g < 4; ++g) bias4[g] = bias[g * H + n];
    if (has_x) {
        #pragma unroll
        for (int g = 0; g < 4; ++g)
            #pragma unroll
            for (int ll = 0; ll < LAG; ++ll)
                a0reg[g][ll] = a0ls[(g * 32 + wx * 16 + li) * LAG + ll];
    }

    #pragma unroll
    for (int mt = 0; mt < 4; ++mt) {
        #pragma unroll
        for (int reg = 0; reg < 4; ++reg) {
            const int b_loc = wy * 64 + mt * 16 + quad * 4 + reg;
            const int b     = bM_ + b_loc;
            float g4[4];
            #pragma unroll
            for (int g = 0; g < 4; ++g) g4[g] = acc[mt][g][reg] + bias4[g];
            if (has_x) {
                #pragma unroll
                for (int ll = 0; ll < LAG; ++ll) {
                    const float xv = xls[b_loc * LAG + ll];
                    #pragma unroll
                    for (int g = 0; g < 4; ++g) g4[g] = fmaf(xv, a0reg[g][ll], g4[g]);
                }
            }
            const float ig = sigf(g4[0]);
            const float fg = sigf(g4[1]);
            const float gg = tanh_fast(g4[2]);
            const float og = sigf(g4[3]);
            const float cold = c_in ? c_in[(size_t)b * H + n] : 0.f;
            const float cnew = fg * cold + ig * gg;
            const float hh   = og * tanh_fast(cnew);
            c_out[(size_t)b * H + n] = cnew;
            if (h32_out) h32_out[(size_t)b * H + n] = hh;
            hb16_out[(size_t)b * 1024 + hcol + n] = __float2bfloat16(hh);
        }
    }
}

// ---------------------------------------------------------------------------
// Per-step scalar head (+ forecast head on last step). One wave per row.
// Reads bf16 h1 from hcat (cols 512..1023).
// ---------------------------------------------------------------------------
__global__ __launch_bounds__(256)
void out_head(const __hip_bfloat16* __restrict__ hcat,
              const float* __restrict__ W_out, const float* __restrict__ b_out,
              const float* __restrict__ W_f,   const float* __restrict__ b_f,
              float* __restrict__ out, int s, int last)
{
    const int wave = threadIdx.x >> 6;
    const int lane = threadIdx.x & 63;
    const int b    = blockIdx.x * 4 + wave;

    const __hip_bfloat16* hrow = hcat + (size_t)b * 1024 + 512;
    short8 hv = *(const short8*)&hrow[lane * 8];
    float h8[8];
    #pragma unroll
    for (int i = 0; i < 8; ++i) {
        union { unsigned int u; float f; } cv;
        cv.u = ((unsigned int)(unsigned short)hv[i]) << 16;
        h8[i] = cv.f;
    }

    {
        const float4 w0 = *reinterpret_cast<const float4*>(&W_out[lane * 8]);
        const float4 w1 = *reinterpret_cast<const float4*>(&W_out[lane * 8 + 4]);
        const float w8[8] = {w0.x, w0.y, w0.z, w0.w, w1.x, w1.y, w1.z, w1.w};
        float v = 0.f;
        #pragma unroll
        for (int i = 0; i < 8; ++i) v = fmaf(h8[i], w8[i], v);
        #pragma unroll
        for (int off = 32; off > 0; off >>= 1) v += __shfl_down(v, off, 64);
        if (lane == 0) out[b * (S + F) + s] = v + b_out[0];
    }
    if (last) {
        for (int f = 0; f < F; ++f) {
            const float4 w0 = *reinterpret_cast<const float4*>(&W_f[f * H + lane * 8]);
            const float4 w1 = *reinterpret_cast<const float4*>(&W_f[f * H + lane * 8 + 4]);
            const float w8[8] = {w0.x, w0.y, w0.z, w0.w, w1.x, w1.y, w1.z, w1.w};
            float v = 0.f;
            #pragma unroll
            for (int i = 0; i < 8; ++i) v = fmaf(h8[i], w8[i], v);
            #pragma unroll
            for (int off = 32; off > 0; off >>= 1) v += __shfl_down(v, off, 64);
            if (lane == 0) out[b * (S + F) + S + f] = v + b_f[f];
        }
    }
}

// ---------------------------------------------------------------------------
extern "C" void kernel_launch(void* const* d_in, const int* in_sizes, int n_in,
                              void* d_out, int out_size, void* d_ws, size_t ws_size,
                              hipStream_t stream)
{
    const float* x     = (const float*)d_in[0];
    const float* W_in  = (const float*)d_in[1];
    const float* b_in  = (const float*)d_in[2];
    const float* Wih0  = (const float*)d_in[3];
    const float* Whh0  = (const float*)d_in[4];
    const float* bih0  = (const float*)d_in[5];
    const float* bhh0  = (const float*)d_in[6];
    const float* Wih1  = (const float*)d_in[7];
    const float* Whh1  = (const float*)d_in[8];
    const float* bih1  = (const float*)d_in[9];
    const float* bhh1  = (const float*)d_in[10];
    const float* W_out = (const float*)d_in[11];
    const float* b_out = (const float*)d_in[12];
    const float* W_f   = (const float*)d_in[13];
    const float* b_f   = (const float*)d_in[14];

    float* out = (float*)d_out;
    char*  ws  = (char*)d_ws;

    // workspace layout
    __hip_bfloat16* hcat0 = (__hip_bfloat16*)ws;                    // [B,1024]
    __hip_bfloat16* hcat1 = hcat0 + (size_t)Bsz * 1024;             // [B,1024]
    __hip_bfloat16* W0b   = hcat1 + (size_t)Bsz * 1024;             // [2048,512]
    __hip_bfloat16* W1b   = W0b + (size_t)G4 * H;                   // [2048,1024]
    float* A0r = (float*)(W1b + (size_t)G4 * 2 * H);                // [2048,5]
    float* b0r = A0r + G4 * LAG;
    float* b1r = b0r + G4;

    // d_out sections as state
    float* hn0 = out + OUT_HN;            // h0 fp32 (last step only)
    float* hn1 = out + OUT_HN + BH;       // h1 fp32 (last step only)
    float* c0  = out + OUT_CN;            // c0 in place
    float* c1  = out + OUT_CN + BH;       // c1 in place

    prep_kernel<<<dim3(G4), dim3(256), 0, stream>>>(
        W_in, b_in, Wih0, Whh0, bih0, bhh0, Wih1, Whh1, bih1, bhh1,
        W0b, W1b, A0r, b0r, b1r);

    // Buffer scheme (contiguous-A): at step s, "cur" = hbuf[s&1], "nxt" =
    // hbuf[(s+1)&1].  L0(s) writes h0(s) -> cur cols 0-511 (reads h0(s-1)
    // from nxt cols 0-511, written by L0(s-1)).  L1(s) reads CONTIGUOUS rows
    // of cur = [h0(s) | h1(s-1)] (h1(s-1) written by L1(s-1) into cur cols
    // 512-1023) and writes h1(s) -> nxt cols 512-1023.  out_head(s) reads
    // h1(s) from nxt.
    __hip_bfloat16* hbuf[2] = {hcat0, hcat1};
    const dim3 grid(16, 64);   // 1024 blocks
    const dim3 blk(512);

    for (int s = 0; s < S; ++s) {
        const bool first = (s == 0);
        const bool last  = (s == S - 1);
        __hip_bfloat16* cur = hbuf[s & 1];
        __hip_bfloat16* nxt = hbuf[(s + 1) & 1];

        // layer 0: A = h0(s-1) = nxt cols 0-511, K=512
        if (first)
            lstm_gemm<0><<<grid, blk, 0, stream>>>(
                nullptr, W0b, H, b0r,
                x + (size_t)s * Bsz * LAG, A0r,
                nullptr, c0, nullptr, cur, 0);
        else
            lstm_gemm<16><<<grid, blk, 0, stream>>>(
                nxt, W0b, H, b0r,
                x + (size_t)s * Bsz * LAG, A0r,
                c0, c0, last ? hn0 : nullptr, cur, 0);

        // layer 1: A = cur rows [h0(s) | h1(s-1)], K=1024 (512 at s=0)
        if (first)
            lstm_gemm<16><<<grid, blk, 0, stream>>>(
                cur, W1b, 2 * H, b1r,
                nullptr, nullptr,
                nullptr, c1, nullptr, nxt, H);
        else
            lstm_gemm<32><<<grid, blk, 0, stream>>>(
                cur, W1b, 2 * H, b1r,
                nullptr, nullptr,
                c1, c1, last ? hn1 : nullptr, nxt, H);

        out_head<<<dim3(Bsz / 4), dim3(256), 0, stream>>>(
            nxt, W_out, b_out, W_f, b_f, out, s, last ? 1 : 0);
    }
}